// Round 16
// baseline (109.101 us; speedup 1.0000x reference)
//
#include <hip/hip_runtime.h>
#include <hip/hip_bf16.h>
#include <hip/hip_fp16.h>

#define B_    512
#define NI    1152
#define NO    10
#define BT    16
#define NBT   32           // B_/BT
#define NC    24           // chunks (8 XCD x 3)
#define NCH   48           // n per chunk
#define RNDS  6
#define RN    8            // n per image round

typedef __attribute__((ext_vector_type(8))) short bf16x8;
typedef __attribute__((ext_vector_type(4))) float f32x4;
typedef __attribute__((ext_vector_type(8))) unsigned short u16x8;

// workspace element counts
#define SPART_H    ((size_t)NC * NBT * NO * 256)      // 1,966,080 halfs (3.93 MB)
#define OUTSUM_F32 ((size_t)NBT * NO * 256)           //    81,920 f32  (0.33 MB)
#define XB_US      ((size_t)NBT * NC * RNDS * 1024)   // 4,718,592 us   (9.44 MB)
#define WB_US      ((size_t)NC * RNDS * 12288)        // 1,769,472 us   (3.54 MB)

__device__ inline unsigned short f2bf(float f) {
    __hip_bfloat16 h = __float2bfloat16(f);
    return *reinterpret_cast<unsigned short*>(&h);
}

__device__ __forceinline__ bf16x8 load_cvt8(const float* src) {
    f32x4 v0 = *reinterpret_cast<const f32x4*>(src);
    f32x4 v1 = *reinterpret_cast<const f32x4*>(src + 4);
    u16x8 u = { f2bf(v0[0]), f2bf(v0[1]), f2bf(v0[2]), f2bf(v0[3]),
                f2bf(v1[0]), f2bf(v1[1]), f2bf(v1[2]), f2bf(v1[3]) };
    return *reinterpret_cast<bf16x8*>(&u);
}

// fp16-packed cross-wave reduce + coalesced s_part store (round-10 epilogue)
__device__ __forceinline__ void iter_epilogue(
    uint2 (*red)[NO * 64], const f32x4* sacc, float sc,
    int w, int l, int tid, unsigned short* base)
{
    #pragma unroll
    for (int o = 0; o < NO; ++o) {
        __half2 h01 = __floats2half2_rn(sacc[o][0] * sc, sacc[o][1] * sc);
        __half2 h23 = __floats2half2_rn(sacc[o][2] * sc, sacc[o][3] * sc);
        red[w][o * 64 + l] =
            make_uint2(*reinterpret_cast<unsigned int*>(&h01),
                       *reinterpret_cast<unsigned int*>(&h23));
    }
    __syncthreads();
    for (int g = tid; g < NO * 64; g += 256) {
        uint2 a0 = red[0][g], a1 = red[1][g], a2 = red[2][g], a3 = red[3][g];
        auto h2f2 = [](unsigned int u) {
            __half2 h = *reinterpret_cast<__half2*>(&u);
            return __half22float2(h);
        };
        float2 lo = h2f2(a0.x), l1 = h2f2(a1.x), l2 = h2f2(a2.x), l3 = h2f2(a3.x);
        float2 ho = h2f2(a0.y), h1 = h2f2(a1.y), h2 = h2f2(a2.y), h3 = h2f2(a3.y);
        float2 sl = { (lo.x + l1.x) + (l2.x + l3.x), (lo.y + l1.y) + (l2.y + l3.y) };
        float2 sh = { (ho.x + h1.x) + (h2.x + h3.x), (ho.y + h1.y) + (h2.y + h3.y) };
        __half2 p01 = __floats2half2_rn(sl.x, sl.y);
        __half2 p23 = __floats2half2_rn(sh.x, sh.y);
        *reinterpret_cast<uint2*>(base + (size_t)g * 4) =
            make_uint2(*reinterpret_cast<unsigned int*>(&p01),
                       *reinterpret_cast<unsigned int*>(&p23));
    }
}

// ---- kernel 1: fused cvt (x,W -> bf16 images) + uniform iter0 -----------
__global__ __launch_bounds__(256) void caps_f0(
    const float* __restrict__ x, const float* __restrict__ w,
    unsigned short* __restrict__ xb, unsigned short* __restrict__ wb,
    unsigned short* __restrict__ s_part)
{
    __shared__ uint2 red[4][NO * 64];   // 20,480 B (epilogue only)

    const int tid = threadIdx.x;
    const int wv  = tid >> 6;
    const int l   = tid & 63;
    const int b16 = l & 15;
    const int hi  = l >> 4;
    const int blk = blockIdx.x;
    const int xcd = blk & 7, idx = blk >> 3;
    const int nc  = xcd * 3 + (idx >> 5);
    const int bt  = idx & 31;

    // (a) x -> xb slice for this (bt,nc): 768 granules
    #pragma unroll
    for (int k = 0; k < 3; ++k) {
        const int gid = k * 256 + tid;
        const int r   = gid >> 7, m = gid & 127;
        const int nl  = m >> 4, bl = m & 15;
        const int b   = bt * BT + bl;
        const int n   = nc * NCH + r * RN + nl;
        const size_t img = (size_t)(bt * NC + nc) * RNDS + r;
        bf16x8 u = load_cvt8(x + ((size_t)b * NI + n) * 8);
        *reinterpret_cast<bf16x8*>(xb + (img * 128 + m) * 8) = u;
    }

    // (b) w -> wb share: granules [blk*288, blk*288+288)
    #pragma unroll
    for (int k = 0; k < 2; ++k) {
        const int loc = k * 256 + tid;
        if (loc < 288) {
            const int t    = blk * 288 + loc;
            const int lane = t & 63;
            const int gs   = (t >> 6) % 24;
            const int img  = t / 1536;               // ncw*6+r
            const int h2   = lane >> 4, d = lane & 15;
            const int nl   = gs / 3, oq = gs % 3;
            const int r    = img % RNDS, ncw = img / RNDS;
            const int o    = oq * 4 + h2;
            const int n    = ncw * NCH + r * RN + nl;
            bf16x8 u = (bf16x8){0,0,0,0,0,0,0,0};
            if (o < NO)
                u = load_cvt8(w + ((size_t)o * NI + n) * 128 + d * 8);
            *reinterpret_cast<bf16x8*>(wb + (size_t)t * 8) = u;
        }
    }

    // (c) uniform iter0: wave wv covers n-local wv*12 .. +11, 4n-packed MFMA
    f32x4 sacc[NO];
    #pragma unroll
    for (int o = 0; o < NO; ++o) sacc[o] = (f32x4){0.f, 0.f, 0.f, 0.f};

    const int bg = bt * BT + b16;
    #pragma unroll 1
    for (int g = 0; g < 3; ++g) {
        const int n_lane = nc * NCH + wv * 12 + g * 4 + hi;  // packed k-block hi
        bf16x8 bv4 = load_cvt8(x + ((size_t)bg * NI + n_lane) * 8);
        #pragma unroll
        for (int o = 0; o < NO; ++o) {
            bf16x8 av4 = load_cvt8(w + ((size_t)o * NI + n_lane) * 128 + b16 * 8);
            sacc[o] = __builtin_amdgcn_mfma_f32_16x16x32_bf16(
                av4, bv4, sacc[o], 0, 0, 0);   // sums 4 n per MFMA
        }
    }

    iter_epilogue(red, sacc, 0.1f, wv, l, tid,
                  s_part + ((size_t)nc * NBT + bt) * 2560);
}

// ---- kernels 2,3: fused squash-prologue + routing iteration -------------
// IT=1: outf = squash(s_prev) = out0; write out0 to outsum; emit s_next.
// IT=2: outf = outsum(out0) + squash(s_prev=iter1 partials); emit s_next.
// Ping-pong buffers make the cross-block read/write race-free; the kernel
// boundary is the producer sync. All blocks sharing bt compute bitwise-
// identical squash values (deterministic).
template<int IT>
__global__ __launch_bounds__(256, 3) void caps_itr(
    const unsigned short* __restrict__ xb,
    const unsigned short* __restrict__ wb,
    const unsigned short* __restrict__ s_prev, // [nc][bt][o][64][4] fp16
    float* __restrict__ outsum,                // [bt*10+o][64][4] f32
    unsigned short* __restrict__ s_next)
{
    __shared__ uint2 red[4][NO * 64];   // 20,480 B (epilogue only)

    const int tid = threadIdx.x;
    const int wv  = tid >> 6;
    const int l   = tid & 63;
    const int b16 = l & 15;
    const int hi  = l >> 4;
    const int blk = blockIdx.x;
    const int xcd = blk & 7, idx = blk >> 3;
    const int nc  = xcd * 3 + (idx >> 5);
    const int bt  = idx & 31;

    // prologue: reduce chunks + squash for this bt (replicated per nc-block)
    f32x4 outf[NO];
    #pragma unroll
    for (int o = 0; o < NO; ++o) {
        f32x4 s = (f32x4){0.f, 0.f, 0.f, 0.f};
        #pragma unroll 6
        for (int c = 0; c < NC; ++c) {
            uint2 pk = *reinterpret_cast<const uint2*>(
                s_prev + ((((size_t)c * NBT + bt) * NO + o) * 64 + l) * 4);
            __half2 h01 = *reinterpret_cast<__half2*>(&pk.x);
            __half2 h23 = *reinterpret_cast<__half2*>(&pk.y);
            float2 f01 = __half22float2(h01), f23 = __half22float2(h23);
            s[0] += f01.x; s[1] += f01.y; s[2] += f23.x; s[3] += f23.y;
        }
        float n2 = s[0] * s[0] + s[1] * s[1] + s[2] * s[2] + s[3] * s[3];
        n2 += __shfl_xor(n2, 16, 64);
        n2 += __shfl_xor(n2, 32, 64);   // sum over the 4 hi-groups (all 16 d)
        const float norm  = sqrtf(n2);
        const float scale = n2 / ((1.f + n2) * (norm + 1e-8f));
        f32x4 v = { scale * s[0], scale * s[1], scale * s[2], scale * s[3] };
        if constexpr (IT == 1) {
            *reinterpret_cast<f32x4*>(
                outsum + (((size_t)bt * NO + o) * 64 + l) * 4) = v;  // out0
            outf[o] = v;
        } else {
            f32x4 p = *reinterpret_cast<const f32x4*>(
                outsum + (((size_t)bt * NO + o) * 64 + l) * 4);
            outf[o] = (f32x4){p[0] + v[0], p[1] + v[1], p[2] + v[2], p[3] + v[3]};
        }
    }

    f32x4 sacc[NO];
    #pragma unroll
    for (int o = 0; o < NO; ++o) sacc[o] = (f32x4){0.f, 0.f, 0.f, 0.f};

    const unsigned short* xbase = xb + (size_t)(bt * NC + nc) * (RNDS * 1024);
    const unsigned short* wbase = wb + (size_t)nc * (RNDS * 12288);

    #pragma unroll 1
    for (int r = 0; r < RNDS; ++r) {
        const unsigned short* xr = xbase + (size_t)r * 1024;
        const unsigned short* wr = wbase + (size_t)r * 12288;
        #pragma unroll 1
        for (int i = 0; i < 2; ++i) {
            const int nl = wv * 2 + i;
            bf16x8 bv = *reinterpret_cast<const bf16x8*>(
                xr + nl * 128 + b16 * 8);
            bf16x8 avv[3];
            #pragma unroll
            for (int oq = 0; oq < 3; ++oq)
                avv[oq] = *reinterpret_cast<const bf16x8*>(
                    wr + (nl * 3 + oq) * 512 + l * 8);
            bf16x8 bvt[4];
            #pragma unroll
            for (int t = 0; t < 4; ++t)
                bvt[t] = (hi == t) ? bv : (bf16x8){0,0,0,0,0,0,0,0};

            f32x4 xh[NO];
            float lg[NO];
            #pragma unroll
            for (int oq = 0; oq < 3; ++oq) {
                const int tmax = (oq < 2) ? 4 : 2;
                #pragma unroll
                for (int t = 0; t < tmax; ++t) {
                    const int o = oq * 4 + t;
                    xh[o] = __builtin_amdgcn_mfma_f32_16x16x32_bf16(
                        avv[oq], bvt[t], (f32x4){0.f, 0.f, 0.f, 0.f}, 0, 0, 0);
                    float pp = outf[o][0] * xh[o][0];
                    pp = fmaf(outf[o][1], xh[o][1], pp);
                    pp = fmaf(outf[o][2], xh[o][2], pp);
                    pp = fmaf(outf[o][3], xh[o][3], pp);
                    pp += __shfl_xor(pp, 16, 64);
                    pp += __shfl_xor(pp, 32, 64);
                    lg[o] = pp;
                }
            }
            float sum = 0.f;
            #pragma unroll
            for (int o = 0; o < NO; ++o) { lg[o] = __expf(lg[o]); sum += lg[o]; }
            const float rs = __builtin_amdgcn_rcpf(sum);
            #pragma unroll
            for (int o = 0; o < NO; ++o) {
                const float cc = lg[o] * rs;
                sacc[o][0] = fmaf(cc, xh[o][0], sacc[o][0]);
                sacc[o][1] = fmaf(cc, xh[o][1], sacc[o][1]);
                sacc[o][2] = fmaf(cc, xh[o][2], sacc[o][2]);
                sacc[o][3] = fmaf(cc, xh[o][3], sacc[o][3]);
            }
        }
    }

    iter_epilogue(red, sacc, 1.0f, wv, l, tid,
                  s_next + ((size_t)nc * NBT + bt) * 2560);
}

// ---- kernel 4: final reduce + squash -> dout ----------------------------
__global__ __launch_bounds__(256) void caps_squash_final(
    const unsigned short* __restrict__ s_part,
    float* __restrict__ dout)
{
    __shared__ float sq[256];
    const int bo = blockIdx.x;
    const int t  = threadIdx.x;

    float s = 0.f;
    #pragma unroll 4
    for (int nc = 0; nc < NC; ++nc) {
        __half h = *reinterpret_cast<const __half*>(
            s_part + ((size_t)nc * NBT * NO + bo) * 256 + t);
        s += __half2float(h);
    }

    float n2 = s * s;
    n2 += __shfl_xor(n2, 1, 64);
    n2 += __shfl_xor(n2, 2, 64);       // q-pair reduced
    sq[t] = n2;
    __syncthreads();
    const int base = t & 63;
    n2 = (sq[base] + sq[64 + base]) + (sq[128 + base] + sq[192 + base]);

    const float norm  = sqrtf(n2);
    const float scale = n2 / ((1.f + n2) * (norm + 1e-8f));
    const float v = scale * s;

    const int bt = bo / NO, o = bo - bt * NO;
    const int b16 = (t >> 2) & 15, hi = t >> 6, q = t & 3;
    dout[((size_t)(bt * BT + b16) * NO + o) * 16 + hi * 4 + q] = v;
}

extern "C" void kernel_launch(void* const* d_in, const int* in_sizes, int n_in,
                              void* d_out, int out_size, void* d_ws, size_t ws_size,
                              hipStream_t stream) {
    const float* x = (const float*)d_in[0];   // [512][1152][8]
    const float* w = (const float*)d_in[1];   // [10][1152][16][8]
    float* out = (float*)d_out;               // [512][10][16]

    unsigned short* s_partA = (unsigned short*)d_ws;
    unsigned short* s_partB = s_partA + SPART_H;
    float*          outsum  = (float*)(s_partB + SPART_H);
    unsigned short* xb      = (unsigned short*)(outsum + OUTSUM_F32);
    unsigned short* wb      = xb + XB_US;     // total ws ~= 21.2 MB

    dim3 gI(NBT * NC), bI(256);               // 768 blocks = 3/CU
    dim3 gS(NBT * NO), bS(256);               // 320 blocks

    caps_f0<<<gI, bI, 0, stream>>>(x, w, xb, wb, s_partA);        // cvt + iter0
    caps_itr<1><<<gI, bI, 0, stream>>>(xb, wb, s_partA, outsum, s_partB);
    caps_itr<2><<<gI, bI, 0, stream>>>(xb, wb, s_partB, outsum, s_partA);
    caps_squash_final<<<gS, bS, 0, stream>>>(s_partA, out);
}

// Round 17
// 65.748 us; speedup vs baseline: 1.6594x; 1.6594x over previous
//
#include <hip/hip_runtime.h>
#include <hip/hip_bf16.h>
#include <hip/hip_fp16.h>

#define B_    512
#define NI    1152
#define NO    10
#define BT    16
#define NBT   32           // B_/BT
#define NC    24           // chunks (8 XCD x 3)
#define NCH   48           // n per chunk
#define RNDS  6
#define RN    8            // n per image round

typedef __attribute__((ext_vector_type(8))) short bf16x8;
typedef __attribute__((ext_vector_type(4))) float f32x4;
typedef __attribute__((ext_vector_type(8))) unsigned short u16x8;

// workspace element counts
#define SPART_H    ((size_t)NC * NBT * NO * 256)      // 1,966,080 halfs (3.93 MB)
#define OUTSUM_F32 ((size_t)NBT * NO * 256)           //    81,920 f32  (0.33 MB)
#define XB_US      ((size_t)NBT * NC * RNDS * 1024)   // 4,718,592 us   (9.44 MB)
#define WB_US      ((size_t)NC * RNDS * 12288)        // 1,769,472 us   (3.54 MB)
#define WB2_US     ((size_t)NC * 12 * NO * 512)       // 1,474,560 us   (2.95 MB)

__device__ inline unsigned short f2bf(float f) {
    __hip_bfloat16 h = __float2bfloat16(f);
    return *reinterpret_cast<unsigned short*>(&h);
}

__device__ __forceinline__ bf16x8 load_cvt8(const float* src) {
    f32x4 v0 = *reinterpret_cast<const f32x4*>(src);
    f32x4 v1 = *reinterpret_cast<const f32x4*>(src + 4);
    u16x8 u = { f2bf(v0[0]), f2bf(v0[1]), f2bf(v0[2]), f2bf(v0[3]),
                f2bf(v1[0]), f2bf(v1[1]), f2bf(v1[2]), f2bf(v1[3]) };
    return *reinterpret_cast<bf16x8*>(&u);
}

// fp16-packed cross-wave reduce + coalesced s_part store
__device__ __forceinline__ void iter_epilogue(
    uint2 (*red)[NO * 64], const f32x4* sacc, float sc,
    int w, int l, int tid, unsigned short* base)
{
    #pragma unroll
    for (int o = 0; o < NO; ++o) {
        __half2 h01 = __floats2half2_rn(sacc[o][0] * sc, sacc[o][1] * sc);
        __half2 h23 = __floats2half2_rn(sacc[o][2] * sc, sacc[o][3] * sc);
        red[w][o * 64 + l] =
            make_uint2(*reinterpret_cast<unsigned int*>(&h01),
                       *reinterpret_cast<unsigned int*>(&h23));
    }
    __syncthreads();
    for (int g = tid; g < NO * 64; g += 256) {
        uint2 a0 = red[0][g], a1 = red[1][g], a2 = red[2][g], a3 = red[3][g];
        auto h2f2 = [](unsigned int u) {
            __half2 h = *reinterpret_cast<__half2*>(&u);
            return __half22float2(h);
        };
        float2 lo = h2f2(a0.x), l1 = h2f2(a1.x), l2 = h2f2(a2.x), l3 = h2f2(a3.x);
        float2 ho = h2f2(a0.y), h1 = h2f2(a1.y), h2 = h2f2(a2.y), h3 = h2f2(a3.y);
        float2 sl = { (lo.x + l1.x) + (l2.x + l3.x), (lo.y + l1.y) + (l2.y + l3.y) };
        float2 sh = { (ho.x + h1.x) + (h2.x + h3.x), (ho.y + h1.y) + (h2.y + h3.y) };
        __half2 p01 = __floats2half2_rn(sl.x, sl.y);
        __half2 p23 = __floats2half2_rn(sh.x, sh.y);
        *reinterpret_cast<uint2*>(base + (size_t)g * 4) =
            make_uint2(*reinterpret_cast<unsigned int*>(&p01),
                       *reinterpret_cast<unsigned int*>(&p23));
    }
}

// ---- kernel 1: convert x,W once. W goes to TWO images:
//  wb  (per-n granules, for masked iters)  and  wb2 (packed-4n, for iter0).
__global__ __launch_bounds__(256) void cvt_xw(
    const float* __restrict__ x, const float* __restrict__ w,
    unsigned short* __restrict__ xb, unsigned short* __restrict__ wb,
    unsigned short* __restrict__ wb2)
{
    const int blk = blockIdx.x;
    if (blk < 2304) {
        const int t = blk * 256 + threadIdx.x;     // 589,824 x granules
        const int m   = t & 127;
        const int img = t >> 7;                    // (bt*NC+nc)*6+r
        const int nl  = m >> 4, bl = m & 15;
        const int r   = img % RNDS;
        const int bc  = img / RNDS;
        const int nc  = bc % NC, bt = bc / NC;
        const int b   = bt * BT + bl;
        const int n   = nc * NCH + r * RN + nl;
        bf16x8 u = load_cvt8(x + ((size_t)b * NI + n) * 8);
        *reinterpret_cast<bf16x8*>(xb + (size_t)t * 8) = u;
    } else {
        const int t    = (blk - 2304) * 256 + threadIdx.x;  // 221,184 granules
        const int lane = t & 63;
        const int gs   = (t >> 6) % 24;
        const int img  = t / 1536;                 // nc*6+r
        const int h2   = lane >> 4, d = lane & 15;
        const int nl   = gs / 3, oq = gs % 3;
        const int r    = img % RNDS, nc = img / RNDS;
        const int o    = oq * 4 + h2;
        const int n    = nc * NCH + r * RN + nl;
        bf16x8 u = (bf16x8){0,0,0,0,0,0,0,0};
        if (o < NO) {
            u = load_cvt8(w + ((size_t)o * NI + n) * 128 + d * 8);
            // packed-4n image: granule ((nc*12+g2)*10+o), k-block = n&3, lane=d
            const int g2  = r * 2 + (nl >> 2);
            const int hi2 = nl & 3;
            *reinterpret_cast<bf16x8*>(
                wb2 + (((size_t)nc * 12 + g2) * NO + o) * 512
                    + (hi2 * 16 + d) * 8) = u;
        }
        *reinterpret_cast<bf16x8*>(wb + (size_t)t * 8) = u;
    }
}

// ---- kernel 2: uniform iter0 from the packed images (unmasked MFMA) -----
// Wave wv: groups g = wv*3..wv*3+2; each MFMA sums 4 n via k-blocks.
__global__ __launch_bounds__(256) void caps_it0(
    const unsigned short* __restrict__ xb,
    const unsigned short* __restrict__ wb2,
    unsigned short* __restrict__ s_part)
{
    __shared__ uint2 red[4][NO * 64];

    const int tid = threadIdx.x;
    const int wv  = tid >> 6;
    const int l   = tid & 63;
    const int b16 = l & 15;
    const int hi  = l >> 4;
    const int blk = blockIdx.x;
    const int xcd = blk & 7, idx = blk >> 3;
    const int nc  = xcd * 3 + (idx >> 5);
    const int bt  = idx & 31;

    f32x4 sacc[NO];
    #pragma unroll
    for (int o = 0; o < NO; ++o) sacc[o] = (f32x4){0.f, 0.f, 0.f, 0.f};

    const unsigned short* xbase = xb + (size_t)(bt * NC + nc) * (RNDS * 1024);
    const unsigned short* w2base = wb2 + (size_t)nc * (12 * NO * 512);

    #pragma unroll 1
    for (int gi = 0; gi < 3; ++gi) {
        const int g  = wv * 3 + gi;
        const int nn = 4 * g + hi;                 // chunk-local n for this lane
        const int r  = nn >> 3, nl = nn & 7;
        bf16x8 bv4 = *reinterpret_cast<const bf16x8*>(
            xbase + (size_t)r * 1024 + (nl * 16 + b16) * 8);
        #pragma unroll
        for (int o = 0; o < NO; ++o) {
            bf16x8 av4 = *reinterpret_cast<const bf16x8*>(
                w2base + ((size_t)g * NO + o) * 512 + l * 8);
            sacc[o] = __builtin_amdgcn_mfma_f32_16x16x32_bf16(
                av4, bv4, sacc[o], 0, 0, 0);       // sums 4 n per MFMA
        }
    }

    iter_epilogue(red, sacc, 0.1f, wv, l, tid,
                  s_part + ((size_t)nc * NBT + bt) * 2560);
}

// ---- kernels 3,5: routing iteration (R15 verbatim: no LDS staging) ------
__global__ __launch_bounds__(256, 3) void caps_itr(
    const unsigned short* __restrict__ xb,
    const unsigned short* __restrict__ wb,
    const float* __restrict__ outsum,    // [bt*10+o][64][4] lane-major f32
    unsigned short* __restrict__ s_part) // [nc][bt][o][64][4] fp16
{
    __shared__ uint2 red[4][NO * 64];

    const int tid = threadIdx.x;
    const int wv  = tid >> 6;
    const int l   = tid & 63;
    const int b16 = l & 15;
    const int hi  = l >> 4;
    const int blk = blockIdx.x;
    const int xcd = blk & 7, idx = blk >> 3;
    const int nc  = xcd * 3 + (idx >> 5);
    const int bt  = idx & 31;

    f32x4 outf[NO];
    #pragma unroll
    for (int o = 0; o < NO; ++o)
        outf[o] = *reinterpret_cast<const f32x4*>(
            outsum + (((size_t)bt * NO + o) * 64 + l) * 4);

    f32x4 sacc[NO];
    #pragma unroll
    for (int o = 0; o < NO; ++o) sacc[o] = (f32x4){0.f, 0.f, 0.f, 0.f};

    const unsigned short* xbase = xb + (size_t)(bt * NC + nc) * (RNDS * 1024);
    const unsigned short* wbase = wb + (size_t)nc * (RNDS * 12288);

    #pragma unroll 1
    for (int r = 0; r < RNDS; ++r) {
        const unsigned short* xr = xbase + (size_t)r * 1024;
        const unsigned short* wr = wbase + (size_t)r * 12288;
        #pragma unroll 1
        for (int i = 0; i < 2; ++i) {
            const int nl = wv * 2 + i;
            bf16x8 bv = *reinterpret_cast<const bf16x8*>(
                xr + nl * 128 + b16 * 8);
            bf16x8 avv[3];
            #pragma unroll
            for (int oq = 0; oq < 3; ++oq)
                avv[oq] = *reinterpret_cast<const bf16x8*>(
                    wr + (nl * 3 + oq) * 512 + l * 8);
            bf16x8 bvt[4];
            #pragma unroll
            for (int t = 0; t < 4; ++t)
                bvt[t] = (hi == t) ? bv : (bf16x8){0,0,0,0,0,0,0,0};

            f32x4 xh[NO];
            float lg[NO];
            #pragma unroll
            for (int oq = 0; oq < 3; ++oq) {
                const int tmax = (oq < 2) ? 4 : 2;
                #pragma unroll
                for (int t = 0; t < tmax; ++t) {
                    const int o = oq * 4 + t;
                    xh[o] = __builtin_amdgcn_mfma_f32_16x16x32_bf16(
                        avv[oq], bvt[t], (f32x4){0.f, 0.f, 0.f, 0.f}, 0, 0, 0);
                    float pp = outf[o][0] * xh[o][0];
                    pp = fmaf(outf[o][1], xh[o][1], pp);
                    pp = fmaf(outf[o][2], xh[o][2], pp);
                    pp = fmaf(outf[o][3], xh[o][3], pp);
                    pp += __shfl_xor(pp, 16, 64);
                    pp += __shfl_xor(pp, 32, 64);
                    lg[o] = pp;
                }
            }
            float sum = 0.f;
            #pragma unroll
            for (int o = 0; o < NO; ++o) { lg[o] = __expf(lg[o]); sum += lg[o]; }
            const float rs = __builtin_amdgcn_rcpf(sum);
            #pragma unroll
            for (int o = 0; o < NO; ++o) {
                const float cc = lg[o] * rs;
                sacc[o][0] = fmaf(cc, xh[o][0], sacc[o][0]);
                sacc[o][1] = fmaf(cc, xh[o][1], sacc[o][1]);
                sacc[o][2] = fmaf(cc, xh[o][2], sacc[o][2]);
                sacc[o][3] = fmaf(cc, xh[o][3], sacc[o][3]);
            }
        }
    }

    iter_epilogue(red, sacc, 1.0f, wv, l, tid,
                  s_part + ((size_t)nc * NBT + bt) * 2560);
}

// ---- squash kernels (R15 verbatim) --------------------------------------
template<int MODE>
__global__ __launch_bounds__(256) void caps_squash(
    const unsigned short* __restrict__ s_part,
    float* __restrict__ outsum,
    float* __restrict__ dout)
{
    __shared__ float sq[256];
    const int bo = blockIdx.x;
    const int t  = threadIdx.x;

    float s = 0.f;
    #pragma unroll 4
    for (int nc = 0; nc < NC; ++nc) {
        __half h = *reinterpret_cast<const __half*>(
            s_part + ((size_t)nc * NBT * NO + bo) * 256 + t);
        s += __half2float(h);
    }

    float n2 = s * s;
    n2 += __shfl_xor(n2, 1, 64);
    n2 += __shfl_xor(n2, 2, 64);       // q-pair reduced
    sq[t] = n2;
    __syncthreads();
    const int base = t & 63;
    n2 = (sq[base] + sq[64 + base]) + (sq[128 + base] + sq[192 + base]);

    const float norm  = sqrtf(n2);
    const float scale = n2 / ((1.f + n2) * (norm + 1e-8f));
    const float v = scale * s;

    if constexpr (MODE == 0) {
        outsum[(size_t)bo * 256 + t] = v;
    } else if constexpr (MODE == 1) {
        outsum[(size_t)bo * 256 + t] += v;
    } else {
        const int bt = bo / NO, o = bo - bt * NO;
        const int b16 = (t >> 2) & 15, hi = t >> 6, q = t & 3;
        dout[((size_t)(bt * BT + b16) * NO + o) * 16 + hi * 4 + q] = v;
    }
}

extern "C" void kernel_launch(void* const* d_in, const int* in_sizes, int n_in,
                              void* d_out, int out_size, void* d_ws, size_t ws_size,
                              hipStream_t stream) {
    const float* x = (const float*)d_in[0];   // [512][1152][8]
    const float* w = (const float*)d_in[1];   // [10][1152][16][8]
    float* out = (float*)d_out;               // [512][10][16]

    unsigned short* s_part = (unsigned short*)d_ws;
    float*          outsum = (float*)(s_part + SPART_H);
    unsigned short* xb     = (unsigned short*)(outsum + OUTSUM_F32);
    unsigned short* wb     = xb + XB_US;
    unsigned short* wb2    = wb + WB_US;      // total ws ~= 20.2 MB

    dim3 gI(NBT * NC), bI(256);               // 768 blocks = 3/CU
    dim3 gS(NBT * NO), bS(256);               // 320 blocks

    cvt_xw<<<dim3(3168), dim3(256), 0, stream>>>(x, w, xb, wb, wb2);
    caps_it0<<<gI, bI, 0, stream>>>(xb, wb2, s_part);
    caps_squash<0><<<gS, bS, 0, stream>>>(s_part, outsum, nullptr);
    caps_itr<<<gI, bI, 0, stream>>>(xb, wb, outsum, s_part);
    caps_squash<1><<<gS, bS, 0, stream>>>(s_part, outsum, nullptr);
    caps_itr<<<gI, bI, 0, stream>>>(xb, wb, outsum, s_part);
    caps_squash<2><<<gS, bS, 0, stream>>>(s_part, nullptr, out);
}